// Round 7
// baseline (287.471 us; speedup 1.0000x reference)
//
#include <hip/hip_runtime.h>

#define BB  8
#define NN1 1024
#define NN2 256
#define DD  16
#define EE  16
#define NCOL (NN2 * DD)   // 4096

using bf16x8  = __attribute__((ext_vector_type(8))) short;
using f32x4   = __attribute__((ext_vector_type(4))) float;
using ushort8 = __attribute__((ext_vector_type(8))) unsigned short;

__device__ __forceinline__ ushort f2bf(float x) {
  unsigned u = __float_as_uint(x);
  unsigned r = (u + 0x7FFFu + ((u >> 16) & 1u)) >> 16;
  return (ushort)r;
}
__device__ __forceinline__ float bf2f(ushort u) {
  return __uint_as_float((unsigned)u << 16);
}
__device__ __forceinline__ unsigned pkbf(float a, float b) {
  return (unsigned)f2bf(a) | ((unsigned)f2bf(b) << 16);
}

#define GLDS16(g, l)                                                       \
  __builtin_amdgcn_global_load_lds(                                        \
      (const __attribute__((address_space(1))) void*)(g),                  \
      (__attribute__((address_space(3))) void*)(l), 16, 0, 0)

// ---------------------------------------------------------------------------
// k_prep: transpose + fp32->bf16 + optional 16B-chunk swizzle.
// src fp32 [kd(k)][nr], dst bf16 [nr][kd].
// ---------------------------------------------------------------------------
__global__ __launch_bounds__(256)
void k_prep(const float* __restrict__ src, ushort* __restrict__ dst,
            int nr, int kd, size_t srcBatch, size_t dstBatch, int swz) {
  __shared__ float tile[64][65];
  const int t = threadIdx.x;
  const int r0 = blockIdx.x * 64;
  const int k0 = blockIdx.y * 64;
  const float* s = src + (size_t)blockIdx.z * srcBatch;
  ushort* d = dst + (size_t)blockIdx.z * dstBatch;

#pragma unroll
  for (int it = 0; it < 4; ++it) {
    const int kr = it * 16 + (t >> 4);
    const int rc = (t & 15) * 4;
    float4 v = *reinterpret_cast<const float4*>(&s[(size_t)(k0 + kr) * nr + r0 + rc]);
    tile[kr][rc] = v.x; tile[kr][rc + 1] = v.y;
    tile[kr][rc + 2] = v.z; tile[kr][rc + 3] = v.w;
  }
  __syncthreads();

#pragma unroll
  for (int pass = 0; pass < 2; ++pass) {
    const int task = t + pass * 256;
    const int pr = task >> 3;
    const int gl = task & 7;
    const int r = r0 + pr;
    const int f = swz ? ((r >> 1) & 3) : 0;
    const int klb = (gl >> 2) * 32 + ((gl & 3) ^ f) * 8;
    unsigned w[4];
#pragma unroll
    for (int e2 = 0; e2 < 4; ++e2)
      w[e2] = pkbf(tile[klb + e2 * 2][pr], tile[klb + e2 * 2 + 1][pr]);
    *reinterpret_cast<uint4*>(&d[(size_t)r * kd + k0 + gl * 8]) =
        *reinterpret_cast<const uint4*>(w);
  }
}

// ---------------------------------------------------------------------------
// k_mode0p: y = adj0^T x (128x128 tile, BK=32, 2-phase pipeline) FUSED with
// the projection epilogue:
//   r[p,j,e] = x[p,j,:]@W + y[p,j,:]@W_s0 + sum(bias)  -> rb bf16 [slice][j][e]
//   s[p,j,e] = x[p,j,:]@W_s1 + y[p,j,:]@W_s01          -> sn bf16 [slice][j][e]
// y never touches HBM: acc -> LDS (swizzled) -> xy A-fragments -> 2 MFMAs.
// grid: x = p-tile (8), y = b*32 + c-tile  (x fast => Xt L2 reuse)
// ---------------------------------------------------------------------------
__global__ __launch_bounds__(256)
void k_mode0p(const ushort* __restrict__ At, const ushort* __restrict__ Xt,
              const float* __restrict__ X,
              ushort* __restrict__ rb, ushort* __restrict__ sn,
              const float* __restrict__ W,   const float* __restrict__ bW,
              const float* __restrict__ W0,  const float* __restrict__ b0,
              const float* __restrict__ W1,  const float* __restrict__ b1,
              const float* __restrict__ W01, const float* __restrict__ b01) {
  __shared__ ushort SH[16384];   // main: As[2](8K us) + Bs[2](8K us); epi: ybuf
  __shared__ ushort RS[4096];    // epilogue r/s flush staging (8 KB)

  const int t = threadIdx.x;
  const int lane = t & 63;
  const int wid = t >> 6;
  const int wm = wid >> 1, wn = wid & 1;
  const int p0 = blockIdx.x << 7;
  const int b  = blockIdx.y >> 5;
  const int c0 = (blockIdx.y & 31) << 7;
  const int j0 = c0 >> 4;

  const ushort* Bb = Xt + (size_t)b * (NCOL * 1024);
  const float*  xb = X  + (size_t)b * ((size_t)NN1 * NCOL);

  ushort* As = SH;          // [2][4096]
  ushort* Bs = SH + 8192;   // [2][4096]

  f32x4 acc[4][4];
#pragma unroll
  for (int i = 0; i < 4; ++i)
#pragma unroll
    for (int j = 0; j < 4; ++j) acc[i][j] = (f32x4)0.f;

  const int srow = wid * 32 + (lane >> 2);
  const int schk = (lane & 3) * 8;
  const size_t aoff0 = (size_t)(p0 + srow) * 1024 + schk;
  const size_t boff0 = (size_t)(c0 + srow) * 1024 + schk;
  const int lw0 = (wid * 32) * 32;
  const int lw1 = (wid * 32 + 16) * 32;

  const int lm = lane & 15, g = lane >> 4;
  int aro[4], bro[4];
#pragma unroll
  for (int f = 0; f < 4; ++f) {
    const int ra = wm * 64 + f * 16 + lm;
    aro[f] = ra * 32 + ((g ^ ((ra >> 1) & 3)) << 3);
    const int rw = wn * 64 + f * 16 + lm;
    bro[f] = rw * 32 + ((g ^ ((rw >> 1) & 3)) << 3);
  }

#define STAGE(buf, kk)                                                     \
  do {                                                                     \
    GLDS16(At + aoff0 + (kk), &As[(buf) * 4096 + lw0]);                    \
    GLDS16(At + aoff0 + 16 * 1024 + (kk), &As[(buf) * 4096 + lw1]);        \
    GLDS16(Bb + boff0 + (kk), &Bs[(buf) * 4096 + lw0]);                    \
    GLDS16(Bb + boff0 + 16 * 1024 + (kk), &Bs[(buf) * 4096 + lw1]);        \
  } while (0)

  STAGE(0, 0);
  int cur = 0;

  for (int k0 = 0; k0 < 1024; k0 += 32) {
    if (k0 + 32 < 1024) {
      STAGE(cur ^ 1, k0 + 32);
      asm volatile("s_waitcnt vmcnt(4)" ::: "memory");
    } else {
      asm volatile("s_waitcnt vmcnt(0)" ::: "memory");
    }
    __builtin_amdgcn_s_barrier();
    __builtin_amdgcn_sched_barrier(0);

    bf16x8 af[4], bfr[4];
#pragma unroll
    for (int f = 0; f < 4; ++f)
      af[f] = *reinterpret_cast<const bf16x8*>(&As[cur * 4096 + aro[f]]);
#pragma unroll
    for (int f = 0; f < 4; ++f)
      bfr[f] = *reinterpret_cast<const bf16x8*>(&Bs[cur * 4096 + bro[f]]);

#pragma unroll
    for (int i = 0; i < 4; ++i)
#pragma unroll
      for (int j = 0; j < 4; ++j)
        acc[i][j] = __builtin_amdgcn_mfma_f32_16x16x32_bf16(af[i], bfr[j], acc[i][j], 0, 0, 0);

    __builtin_amdgcn_sched_barrier(0);
    __builtin_amdgcn_s_barrier();
    cur ^= 1;
  }
#undef STAGE

  // ---------------- epilogue: fused projection ----------------
  // 1. W fragments + bias (same mapping verified in R6's k_pm1)
  const int e = lm;
  bf16x8 wfr, wfs;
#pragma unroll
  for (int jj = 0; jj < 8; ++jj) {
    const int k = g * 8 + jj;
    const float vr = (k < 16) ? W[k * 16 + e]  : W0[(k - 16) * 16 + e];
    const float vs = (k < 16) ? W1[k * 16 + e] : W01[(k - 16) * 16 + e];
    wfr[jj] = (short)f2bf(vr);
    wfs[jj] = (short)f2bf(vs);
  }
  const float bias = bW[e] + b0[e] + b1[e] + b01[e];

  // 2. acc -> ybuf (bf16, XOR-swizzled rows)
#pragma unroll
  for (int i = 0; i < 4; ++i)
#pragma unroll
    for (int jt = 0; jt < 4; ++jt) {
#pragma unroll
      for (int r = 0; r < 4; ++r) {
        const int p = wm * 64 + i * 16 + g * 4 + r;
        const int c = wn * 64 + jt * 16 + lm;
        SH[(p * 128 + c) ^ ((p & 7) << 3)] = f2bf(acc[i][jt][r]);
      }
    }
  __syncthreads();

  // 3. per-j rounds: build xy A-frag, 2 MFMAs, stage to RS, coalesced flush
  for (int jj = 0; jj < 8; ++jj) {
#pragma unroll
    for (int mm = 0; mm < 2; ++mm) {
      const int Mi = wid * 2 + mm;
      const int pA = Mi * 16 + lm;
      // x half (fp32 global; lanes g>=2 load same addrs -> L1 hits)
      const float* xp = xb + (size_t)(p0 + pA) * NCOL + c0 + jj * 16 + (g & 1) * 8;
      const float4 xv0 = *reinterpret_cast<const float4*>(xp);
      const float4 xv1 = *reinterpret_cast<const float4*>(xp + 4);
      bf16x8 xa;
      xa[0] = (short)f2bf(xv0.x); xa[1] = (short)f2bf(xv0.y);
      xa[2] = (short)f2bf(xv0.z); xa[3] = (short)f2bf(xv0.w);
      xa[4] = (short)f2bf(xv1.x); xa[5] = (short)f2bf(xv1.y);
      xa[6] = (short)f2bf(xv1.z); xa[7] = (short)f2bf(xv1.w);
      // y half (LDS, swizzled)
      const int yi = (pA * 128 + jj * 16 + (g & 1) * 8) ^ ((pA & 7) << 3);
      const bf16x8 ya = *reinterpret_cast<const bf16x8*>(&SH[yi]);
      const bf16x8 a = (g < 2) ? xa : ya;

      f32x4 cb; cb[0] = bias; cb[1] = bias; cb[2] = bias; cb[3] = bias;
      const f32x4 rD = __builtin_amdgcn_mfma_f32_16x16x32_bf16(a, wfr, cb, 0, 0, 0);
      const f32x4 sD = __builtin_amdgcn_mfma_f32_16x16x32_bf16(a, wfs, (f32x4)0.f, 0, 0, 0);

#pragma unroll
      for (int r = 0; r < 4; ++r) {
        const int pr = Mi * 16 + g * 4 + r;
        const int x8 = ((pr >> 2) & 1) << 3;
        RS[(pr * 16 + e) ^ x8]        = f2bf(rD[r]);
        RS[(2048 + pr * 16 + e) ^ x8] = f2bf(sD[r]);
      }
    }
    __syncthreads();
    // flush RS -> rb / sn (16B per thread per buffer)
    {
      const int p  = t >> 1;
      const int eh = t & 1;
      const int ch = eh ^ ((p >> 2) & 1);
      const size_t go = (size_t)(b * NN1 + p0 + p) * NCOL + (j0 + jj) * 16 + eh * 8;
      *reinterpret_cast<uint4*>(rb + go) =
          *reinterpret_cast<const uint4*>(&RS[p * 16 + ch * 8]);
      *reinterpret_cast<uint4*>(sn + go) =
          *reinterpret_cast<const uint4*>(&RS[2048 + p * 16 + ch * 8]);
    }
    __syncthreads();
  }
}

// ---------------------------------------------------------------------------
// k_mode1b: C[q][m] = sum_j adj1t[q][j] * s[m][j]  (m = slice*16+e)
// out[slice][q][e] = relu(rb + C).  A: GLDS16 (swizzled prep). B: reg-staged
// from sn [slice][j][e] with LDS transpose scatter. rb: T14 pre-stage to Rs.
// grid: x = q-tile (2, fast => sn shared via L2), y = m-tile (nb*128)
// ---------------------------------------------------------------------------
__global__ __launch_bounds__(256)
void k_mode1b(const ushort* __restrict__ A1t, const ushort* __restrict__ sn,
              const ushort* __restrict__ rb, float* __restrict__ out) {
  __shared__ ushort As[2][4096];   // 128 q x 32 j
  __shared__ ushort Bs[2][4096];   // 128 m x 32 j (transposed, swizzled)
  __shared__ ushort Rs[16384];     // 8 sl x 128 q x 16 e

  const int t = threadIdx.x;
  const int lane = t & 63;
  const int wid = t >> 6;
  const int wm = wid >> 1, wn = wid & 1;
  const int q0  = blockIdx.x << 7;
  const int m0  = blockIdx.y << 7;
  const int sl0 = blockIdx.y << 3;

  // T14: rb pre-stage (drained by first vmcnt(0), ordered by prologue barrier)
#pragma unroll
  for (int k = 0; k < 8; ++k) {
    const ushort* gsrc = rb + (size_t)(sl0 + k) * NCOL + q0 * 16 + (wid * 64 + lane) * 8;
    GLDS16(gsrc, &Rs[k * 2048 + wid * 512]);
  }

  f32x4 acc[4][4];
#pragma unroll
  for (int i = 0; i < 4; ++i)
#pragma unroll
    for (int j = 0; j < 4; ++j) acc[i][j] = (f32x4)0.f;

  const int srow = wid * 32 + (lane >> 2);
  const int schk = (lane & 3) * 8;
  const size_t aoff0 = (size_t)(q0 + srow) * 256 + schk;
  const int lw0 = (wid * 32) * 32;
  const int lw1 = (wid * 32 + 16) * 32;

  const int lm = lane & 15, g = lane >> 4;
  int aro[4], bro[4];
#pragma unroll
  for (int f = 0; f < 4; ++f) {
    const int ra = wm * 64 + f * 16 + lm;
    aro[f] = ra * 32 + ((g ^ ((ra >> 1) & 3)) << 3);
    const int rw = wn * 64 + f * 16 + lm;
    bro[f] = rw * 32 + ((g ^ ((rw >> 1) & 3)) << 3);
  }

  // B reg-stage mapping (per thread, 2 iters)
  int slA[2], jA[2], ehA[2];
#pragma unroll
  for (int it = 0; it < 2; ++it) {
    const int u = t + it * 256;
    slA[it] = u >> 6;
    jA[it]  = (u >> 1) & 31;
    ehA[it] = u & 1;
  }

  uint4 breg[2];
#define BLOAD(kt)                                                          \
  do {                                                                     \
    const int jb = (kt) * 32;                                              \
    _Pragma("unroll")                                                      \
    for (int it = 0; it < 2; ++it)                                         \
      breg[it] = *reinterpret_cast<const uint4*>(                          \
          sn + (size_t)(sl0 + slA[it]) * NCOL + (jb + jA[it]) * 16 + ehA[it] * 8); \
  } while (0)

#define BWRITE(buf)                                                        \
  do {                                                                     \
    _Pragma("unroll")                                                      \
    for (int it = 0; it < 2; ++it) {                                       \
      const ushort8 v = *reinterpret_cast<const ushort8*>(&breg[it]);      \
      _Pragma("unroll")                                                    \
      for (int q = 0; q < 8; ++q) {                                        \
        const int m = slA[it] * 16 + ehA[it] * 8 + q;                      \
        Bs[buf][(m * 32 + jA[it]) ^ (((m >> 1) & 3) << 3)] = v[q];         \
      }                                                                    \
    }                                                                      \
  } while (0)

#define ASTG(buf, kb)                                                      \
  do {                                                                     \
    GLDS16(A1t + aoff0 + (kb), &As[buf][lw0]);                             \
    GLDS16(A1t + aoff0 + 16 * 256 + (kb), &As[buf][lw1]);                  \
  } while (0)

  // prologue
  BLOAD(0);
  ASTG(0, 0);
  asm volatile("s_waitcnt vmcnt(0)" ::: "memory");
  BWRITE(0);
  __syncthreads();

  int cur = 0;
  for (int kt = 0; kt < 8; ++kt) {
    if (kt < 7) {
      BLOAD(kt + 1);
      ASTG(cur ^ 1, (kt + 1) * 32);
    }

    bf16x8 af[4], bfr[4];
#pragma unroll
    for (int f = 0; f < 4; ++f) af[f] = *reinterpret_cast<const bf16x8*>(&As[cur][aro[f]]);
#pragma unroll
    for (int f = 0; f < 4; ++f) bfr[f] = *reinterpret_cast<const bf16x8*>(&Bs[cur][bro[f]]);

#pragma unroll
    for (int i = 0; i < 4; ++i)
#pragma unroll
      for (int j = 0; j < 4; ++j)
        acc[i][j] = __builtin_amdgcn_mfma_f32_16x16x32_bf16(af[i], bfr[j], acc[i][j], 0, 0, 0);

    if (kt < 7) BWRITE(cur ^ 1);
    asm volatile("s_waitcnt vmcnt(0)" ::: "memory");
    __syncthreads();
    cur ^= 1;
  }
#undef BLOAD
#undef BWRITE
#undef ASTG

  const int orow = g * 4;   // q offset
#pragma unroll
  for (int i = 0; i < 4; ++i)
#pragma unroll
    for (int j = 0; j < 4; ++j) {
      const int ml  = wn * 64 + j * 16 + lm;
      const int bpl = ml >> 4, e = ml & 15;
      const int ql  = wm * 64 + i * 16 + orow;
      const ushort* rsl = &Rs[bpl * 2048 + ql * 16 + e];
      float* dst = out + (size_t)(sl0 + bpl) * (NN2 * EE) + (size_t)(q0 + ql) * EE + e;
#pragma unroll
      for (int r = 0; r < 4; ++r)
        dst[r * EE] = fmaxf(bf2f(rsl[r * 16]) + acc[i][j][r], 0.f);
    }
}

// ---------------------------------------------------------------------------
extern "C" void kernel_launch(void* const* d_in, const int* in_sizes, int n_in,
                              void* d_out, int out_size, void* d_ws, size_t ws_size,
                              hipStream_t stream) {
  const float* x    = (const float*)d_in[0];
  const float* adj0 = (const float*)d_in[1];
  const float* adj1 = (const float*)d_in[2];
  const float* W    = (const float*)d_in[3];
  const float* bW   = (const float*)d_in[4];
  const float* Ws0  = (const float*)d_in[5];
  const float* bs0  = (const float*)d_in[6];
  const float* Ws1  = (const float*)d_in[7];
  const float* bs1  = (const float*)d_in[8];
  const float* Ws01 = (const float*)d_in[9];
  const float* bs01 = (const float*)d_in[10];
  float* out = (float*)d_out;

  const size_t SLICE = (size_t)NN1 * NCOL;
  const size_t AT_B  = (size_t)1024 * 1024 * 2;       // adj0^T bf16 swz
  const size_t A1T_B = (size_t)256 * 256 * 2;         // adj1^T bf16 swz
  const size_t XT_B  = (size_t)NCOL * 1024 * 2;       // per-batch, 8.4 MB
  const size_t RB_B  = SLICE * 2;                     // per-batch, 8.4 MB
  const size_t SN_B  = SLICE * 2;                     // per-batch, 8.4 MB
  const size_t HEAD  = AT_B + A1T_B;
  const size_t PER_B = XT_B + RB_B + SN_B;

  int nb_max = (int)((ws_size > HEAD ? ws_size - HEAD : 0) / PER_B);
  if (nb_max > BB) nb_max = BB;
  if (nb_max < 1)  nb_max = 1;

  ushort* At  = (ushort*)d_ws;
  ushort* A1t = (ushort*)((char*)d_ws + AT_B);
  ushort* Xt  = (ushort*)((char*)d_ws + HEAD);
  ushort* rb  = (ushort*)((char*)d_ws + HEAD + (size_t)nb_max * XT_B);
  ushort* sn  = (ushort*)((char*)d_ws + HEAD + (size_t)nb_max * (XT_B + RB_B));

  k_prep<<<dim3(16, 16, 1), 256, 0, stream>>>(adj0, At, 1024, 1024, 0, 0, 1);
  k_prep<<<dim3(4, 4, 1), 256, 0, stream>>>(adj1, A1t, 256, 256, 0, 0, 1);

  for (int c0 = 0; c0 < BB; c0 += nb_max) {
    const int nb = (BB - c0 < nb_max) ? (BB - c0) : nb_max;
    const float* xc = x   + (size_t)c0 * SLICE;
    float*       oc = out + (size_t)c0 * SLICE;

    k_prep<<<dim3(NCOL / 64, 16, nb), 256, 0, stream>>>(
        xc, Xt, NCOL, 1024, SLICE, (size_t)NCOL * 1024, 1);

    dim3 g1(8, nb * 32);
    k_mode0p<<<g1, 256, 0, stream>>>(At, Xt, xc, rb, sn,
                                     W, bW, Ws0, bs0, Ws1, bs1, Ws01, bs01);

    dim3 g2(2, nb * 128);
    k_mode1b<<<g2, 256, 0, stream>>>(A1t, sn, rb, oc);
  }
}

// Round 8
// 280.044 us; speedup vs baseline: 1.0265x; 1.0265x over previous
//
#include <hip/hip_runtime.h>

#define BB  8
#define NN1 1024
#define NN2 256
#define DD  16
#define EE  16
#define NCOL (NN2 * DD)   // 4096

using bf16x8  = __attribute__((ext_vector_type(8))) short;
using f32x4   = __attribute__((ext_vector_type(4))) float;
using ushort8 = __attribute__((ext_vector_type(8))) unsigned short;

__device__ __forceinline__ ushort f2bf(float x) {
  unsigned u = __float_as_uint(x);
  unsigned r = (u + 0x7FFFu + ((u >> 16) & 1u)) >> 16;
  return (ushort)r;
}
__device__ __forceinline__ float bf2f(ushort u) {
  return __uint_as_float((unsigned)u << 16);
}
__device__ __forceinline__ unsigned pkbf(float a, float b) {
  return (unsigned)f2bf(a) | ((unsigned)f2bf(b) << 16);
}

#define GLDS16(g, l)                                                       \
  __builtin_amdgcn_global_load_lds(                                        \
      (const __attribute__((address_space(1))) void*)(g),                  \
      (__attribute__((address_space(3))) void*)(l), 16, 0, 0)

// ---------------------------------------------------------------------------
// k_prep: transpose + fp32->bf16 + 16B-chunk swizzle.
// src fp32 [kd(k)][nr], dst bf16 [nr][kd], chunk g <- g ^ ((row>>1)&3) per 64B.
// ---------------------------------------------------------------------------
__global__ __launch_bounds__(256)
void k_prep(const float* __restrict__ src, ushort* __restrict__ dst,
            int nr, int kd, size_t srcBatch, size_t dstBatch) {
  __shared__ float tile[64][65];
  const int t = threadIdx.x;
  const int r0 = blockIdx.x * 64;
  const int k0 = blockIdx.y * 64;
  const float* s = src + (size_t)blockIdx.z * srcBatch;
  ushort* d = dst + (size_t)blockIdx.z * dstBatch;

#pragma unroll
  for (int it = 0; it < 4; ++it) {
    const int kr = it * 16 + (t >> 4);
    const int rc = (t & 15) * 4;
    float4 v = *reinterpret_cast<const float4*>(&s[(size_t)(k0 + kr) * nr + r0 + rc]);
    tile[kr][rc] = v.x; tile[kr][rc + 1] = v.y;
    tile[kr][rc + 2] = v.z; tile[kr][rc + 3] = v.w;
  }
  __syncthreads();

#pragma unroll
  for (int pass = 0; pass < 2; ++pass) {
    const int task = t + pass * 256;
    const int pr = task >> 3;
    const int gl = task & 7;
    const int r = r0 + pr;
    const int f = (r >> 1) & 3;
    const int klb = (gl >> 2) * 32 + ((gl & 3) ^ f) * 8;
    unsigned w[4];
#pragma unroll
    for (int e2 = 0; e2 < 4; ++e2)
      w[e2] = pkbf(tile[klb + e2 * 2][pr], tile[klb + e2 * 2 + 1][pr]);
    *reinterpret_cast<uint4*>(&d[(size_t)r * kd + k0 + gl * 8]) =
        *reinterpret_cast<const uint4*>(w);
  }
}

// ---------------------------------------------------------------------------
// k_mode0_mfma: y[b][p][c] = sum_k adj0[k][p] * X[b][k][c] -> bf16
// 128x128 tile, BK=32, 2-phase pipeline, counted vmcnt(4), raw s_barrier.
// ---------------------------------------------------------------------------
__global__ __launch_bounds__(256)
void k_mode0_mfma(const ushort* __restrict__ At, const ushort* __restrict__ Xt,
                  ushort* __restrict__ Y) {
  __shared__ ushort As[2][4096];
  __shared__ ushort Bs[2][4096];

  const int t = threadIdx.x;
  const int lane = t & 63;
  const int wid = t >> 6;
  const int wm = wid >> 1, wn = wid & 1;
  const int b  = blockIdx.x >> 5;
  const int c0 = (blockIdx.x & 31) << 7;
  const int p0 = blockIdx.y << 7;

  const ushort* Bb = Xt + (size_t)b * (NCOL * 1024);

  f32x4 acc[4][4];
#pragma unroll
  for (int i = 0; i < 4; ++i)
#pragma unroll
    for (int j = 0; j < 4; ++j) acc[i][j] = (f32x4)0.f;

  const int srow = wid * 32 + (lane >> 2);
  const int schk = (lane & 3) * 8;
  const size_t aoff0 = (size_t)(p0 + srow) * 1024 + schk;
  const size_t boff0 = (size_t)(c0 + srow) * 1024 + schk;
  const int lw0 = (wid * 32) * 32;
  const int lw1 = (wid * 32 + 16) * 32;

  const int lm = lane & 15, g = lane >> 4;
  int aro[4], bro[4];
#pragma unroll
  for (int f = 0; f < 4; ++f) {
    const int ra = wm * 64 + f * 16 + lm;
    aro[f] = ra * 32 + ((g ^ ((ra >> 1) & 3)) << 3);
    const int rw = wn * 64 + f * 16 + lm;
    bro[f] = rw * 32 + ((g ^ ((rw >> 1) & 3)) << 3);
  }

#define STAGE0(buf, kk)                                                    \
  do {                                                                     \
    GLDS16(At + aoff0 + (kk), &As[buf][lw0]);                              \
    GLDS16(At + aoff0 + 16 * 1024 + (kk), &As[buf][lw1]);                  \
    GLDS16(Bb + boff0 + (kk), &Bs[buf][lw0]);                              \
    GLDS16(Bb + boff0 + 16 * 1024 + (kk), &Bs[buf][lw1]);                  \
  } while (0)

  STAGE0(0, 0);
  int cur = 0;

  for (int k0 = 0; k0 < 1024; k0 += 32) {
    if (k0 + 32 < 1024) {
      STAGE0(cur ^ 1, k0 + 32);
      asm volatile("s_waitcnt vmcnt(4)" ::: "memory");
    } else {
      asm volatile("s_waitcnt vmcnt(0)" ::: "memory");
    }
    __builtin_amdgcn_s_barrier();
    __builtin_amdgcn_sched_barrier(0);

    bf16x8 af[4], bfr[4];
#pragma unroll
    for (int f = 0; f < 4; ++f)
      af[f] = *reinterpret_cast<const bf16x8*>(&As[cur][aro[f]]);
#pragma unroll
    for (int f = 0; f < 4; ++f)
      bfr[f] = *reinterpret_cast<const bf16x8*>(&Bs[cur][bro[f]]);

#pragma unroll
    for (int i = 0; i < 4; ++i)
#pragma unroll
      for (int j = 0; j < 4; ++j)
        acc[i][j] = __builtin_amdgcn_mfma_f32_16x16x32_bf16(af[i], bfr[j], acc[i][j], 0, 0, 0);

    __builtin_amdgcn_sched_barrier(0);
    __builtin_amdgcn_s_barrier();
    cur ^= 1;
  }
#undef STAGE0

  ushort* Yb = Y + (size_t)b * (NN1 * NCOL);
  const int orow = g * 4;
  const int ocol = lm;
#pragma unroll
  for (int i = 0; i < 4; ++i)
#pragma unroll
    for (int j = 0; j < 4; ++j) {
      const int p = p0 + wm * 64 + i * 16 + orow;
      const int c = c0 + wn * 64 + j * 16 + ocol;
      ushort* dst = Yb + (size_t)p * NCOL + c;
#pragma unroll
      for (int e = 0; e < 4; ++e) dst[(size_t)e * NCOL] = f2bf(acc[i][j][e]);
    }
}

// ---------------------------------------------------------------------------
// k_proj: per (b,p) slice, thread j:
//   r[j,e] = x@W + y0@W_s0 + sum(bias)  -> rb (bf16, [slice][j][e])
//   s[j,e] = x@W_s1 + y0@W_s01          -> st (bf16, swizzled, [slice*16+e][j])
// ---------------------------------------------------------------------------
__global__ __launch_bounds__(256)
void k_proj(const float* __restrict__ x, const ushort* __restrict__ y0,
            ushort* __restrict__ st, ushort* __restrict__ rb,
            const float* __restrict__ W,   const float* __restrict__ bW,
            const float* __restrict__ W0,  const float* __restrict__ b0,
            const float* __restrict__ W1,  const float* __restrict__ b1,
            const float* __restrict__ W01, const float* __restrict__ b01) {
  __shared__ float sW[4][DD][EE];
  __shared__ float sbias[EE];

  const int t = threadIdx.x;
  {
    const int m = t >> 6;
    const int r = t & 63;
    const float* Wp = (m == 0) ? W : (m == 1) ? W0 : (m == 2) ? W1 : W01;
    reinterpret_cast<float4*>(&sW[m][0][0])[r] =
        reinterpret_cast<const float4*>(Wp)[r];
  }
  if (t < EE) sbias[t] = bW[t] + b0[t] + b1[t] + b01[t];
  __syncthreads();

  const size_t base = (size_t)blockIdx.x * NCOL + (size_t)t * DD;

  float xr[DD], yr[DD];
#pragma unroll
  for (int v = 0; v < 4; ++v)
    *reinterpret_cast<float4*>(&xr[v * 4]) =
        *reinterpret_cast<const float4*>(&x[base + v * 4]);
  {
    ushort8 ya = *reinterpret_cast<const ushort8*>(&y0[base]);
    ushort8 yb = *reinterpret_cast<const ushort8*>(&y0[base + 8]);
#pragma unroll
    for (int k = 0; k < 8; ++k) { yr[k] = bf2f(ya[k]); yr[8 + k] = bf2f(yb[k]); }
  }

  float r[EE], s[EE];
#pragma unroll
  for (int e = 0; e < EE; ++e) { r[e] = sbias[e]; s[e] = 0.f; }

#pragma unroll
  for (int d = 0; d < DD; ++d) {
    const float xd = xr[d], yd = yr[d];
#pragma unroll
    for (int e = 0; e < EE; ++e) {
      r[e] = fmaf(xd, sW[0][d][e], r[e]);
      r[e] = fmaf(yd, sW[1][d][e], r[e]);
      s[e] = fmaf(xd, sW[2][d][e], s[e]);
      s[e] = fmaf(yd, sW[3][d][e], s[e]);
    }
  }

  // r -> bf16, [slice][j][e]
  {
    ushort rw[16];
#pragma unroll
    for (int e = 0; e < EE; ++e) rw[e] = f2bf(r[e]);
    *reinterpret_cast<uint4*>(&rb[base])     = *reinterpret_cast<const uint4*>(&rw[0]);
    *reinterpret_cast<uint4*>(&rb[base + 8]) = *reinterpret_cast<const uint4*>(&rw[8]);
  }

  // st row = slice*16+e, chunk-swizzled within 64B blocks ((m>>1)&3 == (e>>1)&3)
  const size_t stbase = (size_t)blockIdx.x * (EE * NN2);
#pragma unroll
  for (int e = 0; e < EE; ++e) {
    const int f = (e >> 1) & 3;
    const int off = (t >> 5) * 32 + ((((t >> 3) & 3) ^ f) << 3) + (t & 7);
    st[stbase + (size_t)e * NN2 + off] = f2bf(s[e]);
  }
}

// ---------------------------------------------------------------------------
// k_mode1c: C[q][m] = sum_j adj1t[q][j] * st[m][j]   (m = slice*16+e)
// out[slice][q][e] = relu(rb + C).  A,B both GLDS16-staged (linear, swizzled
// prep), 2-phase counted-vmcnt pipeline, T14 rb pre-stage into Rs.
// grid: x = q-tile (2, fast), y = m-tile (nb*128)
// ---------------------------------------------------------------------------
__global__ __launch_bounds__(256)
void k_mode1c(const ushort* __restrict__ A1t, const ushort* __restrict__ st,
              const ushort* __restrict__ rb, float* __restrict__ out) {
  __shared__ ushort As[2][4096];
  __shared__ ushort Bs[2][4096];
  __shared__ ushort Rs[16384];     // 8 sl x 128 q x 16 e

  const int t = threadIdx.x;
  const int lane = t & 63;
  const int wid = t >> 6;
  const int wm = wid >> 1, wn = wid & 1;
  const int q0  = blockIdx.x << 7;
  const int m0  = blockIdx.y << 7;
  const int sl0 = blockIdx.y << 3;

  // T14: rb pre-stage; drained by the first in-loop vmcnt(4) (8+4 oldest)
#pragma unroll
  for (int k = 0; k < 8; ++k) {
    const ushort* gsrc = rb + (size_t)(sl0 + k) * NCOL + q0 * 16 + (wid * 64 + lane) * 8;
    GLDS16(gsrc, &Rs[k * 2048 + wid * 512]);
  }

  f32x4 acc[4][4];
#pragma unroll
  for (int i = 0; i < 4; ++i)
#pragma unroll
    for (int j = 0; j < 4; ++j) acc[i][j] = (f32x4)0.f;

  const int srow = wid * 32 + (lane >> 2);
  const int schk = (lane & 3) * 8;
  const size_t aoff0 = (size_t)(q0 + srow) * 256 + schk;
  const size_t boff0 = (size_t)(m0 + srow) * 256 + schk;
  const int lw0 = (wid * 32) * 32;
  const int lw1 = (wid * 32 + 16) * 32;

  const int lm = lane & 15, g = lane >> 4;
  int aro[4], bro[4];
#pragma unroll
  for (int f = 0; f < 4; ++f) {
    const int ra = wm * 64 + f * 16 + lm;
    aro[f] = ra * 32 + ((g ^ ((ra >> 1) & 3)) << 3);
    const int rw = wn * 64 + f * 16 + lm;
    bro[f] = rw * 32 + ((g ^ ((rw >> 1) & 3)) << 3);
  }

#define STAGE1(buf, kk)                                                    \
  do {                                                                     \
    GLDS16(A1t + aoff0 + (kk), &As[buf][lw0]);                             \
    GLDS16(A1t + aoff0 + 16 * 256 + (kk), &As[buf][lw1]);                  \
    GLDS16(st + boff0 + (kk), &Bs[buf][lw0]);                              \
    GLDS16(st + boff0 + 16 * 256 + (kk), &Bs[buf][lw1]);                   \
  } while (0)

  STAGE1(0, 0);
  int cur = 0;

  for (int k0 = 0; k0 < 256; k0 += 32) {
    if (k0 + 32 < 256) {
      STAGE1(cur ^ 1, k0 + 32);
      asm volatile("s_waitcnt vmcnt(4)" ::: "memory");
    } else {
      asm volatile("s_waitcnt vmcnt(0)" ::: "memory");
    }
    __builtin_amdgcn_s_barrier();
    __builtin_amdgcn_sched_barrier(0);

    bf16x8 af[4], bfr[4];
#pragma unroll
    for (int f = 0; f < 4; ++f)
      af[f] = *reinterpret_cast<const bf16x8*>(&As[cur][aro[f]]);
#pragma unroll
    for (int f = 0; f < 4; ++f)
      bfr[f] = *reinterpret_cast<const bf16x8*>(&Bs[cur][bro[f]]);

#pragma unroll
    for (int i = 0; i < 4; ++i)
#pragma unroll
      for (int j = 0; j < 4; ++j)
        acc[i][j] = __builtin_amdgcn_mfma_f32_16x16x32_bf16(af[i], bfr[j], acc[i][j], 0, 0, 0);

    __builtin_amdgcn_sched_barrier(0);
    __builtin_amdgcn_s_barrier();
    cur ^= 1;
  }
#undef STAGE1

  const int orow = g * 4;
#pragma unroll
  for (int i = 0; i < 4; ++i)
#pragma unroll
    for (int j = 0; j < 4; ++j) {
      const int ml  = wn * 64 + j * 16 + lm;
      const int bpl = ml >> 4, e = ml & 15;
      const int ql  = wm * 64 + i * 16 + orow;
      const ushort* rsl = &Rs[bpl * 2048 + ql * 16 + e];
      float* dst = out + (size_t)(sl0 + bpl) * NCOL + (size_t)(q0 + ql) * EE + e;
#pragma unroll
      for (int r = 0; r < 4; ++r)
        dst[r * EE] = fmaxf(bf2f(rsl[r * 16]) + acc[i][j][r], 0.f);
    }
}

// ---------------------------------------------------------------------------
extern "C" void kernel_launch(void* const* d_in, const int* in_sizes, int n_in,
                              void* d_out, int out_size, void* d_ws, size_t ws_size,
                              hipStream_t stream) {
  const float* x    = (const float*)d_in[0];
  const float* adj0 = (const float*)d_in[1];
  const float* adj1 = (const float*)d_in[2];
  const float* W    = (const float*)d_in[3];
  const float* bW   = (const float*)d_in[4];
  const float* Ws0  = (const float*)d_in[5];
  const float* bs0  = (const float*)d_in[6];
  const float* Ws1  = (const float*)d_in[7];
  const float* bs1  = (const float*)d_in[8];
  const float* Ws01 = (const float*)d_in[9];
  const float* bs01 = (const float*)d_in[10];
  float* out = (float*)d_out;

  const size_t SLICE = (size_t)NN1 * NCOL;
  const size_t AT_B  = (size_t)1024 * 1024 * 2;       // adj0^T bf16 swz
  const size_t A1T_B = (size_t)256 * 256 * 2;         // adj1^T bf16 swz
  const size_t XT_B  = (size_t)NCOL * 1024 * 2;       // per-batch, 8.4 MB
  const size_t Y0_B  = SLICE * 2;                     // per-batch bf16
  const size_t ST_B  = SLICE * 2;                     // per-batch
  const size_t RB_B  = SLICE * 2;                     // per-batch
  const size_t HEAD  = AT_B + A1T_B;
  const size_t PER_B = XT_B + Y0_B + ST_B + RB_B;

  int nb_max = (int)((ws_size > HEAD ? ws_size - HEAD : 0) / PER_B);
  if (nb_max > BB) nb_max = BB;
  if (nb_max < 1)  nb_max = 1;

  ushort* At  = (ushort*)d_ws;
  ushort* A1t = (ushort*)((char*)d_ws + AT_B);
  ushort* Xt  = (ushort*)((char*)d_ws + HEAD);
  ushort* y0  = (ushort*)((char*)d_ws + HEAD + (size_t)nb_max * XT_B);
  ushort* st  = (ushort*)((char*)d_ws + HEAD + (size_t)nb_max * (XT_B + Y0_B));
  ushort* rb  = (ushort*)((char*)d_ws + HEAD + (size_t)nb_max * (XT_B + Y0_B + ST_B));

  k_prep<<<dim3(16, 16, 1), 256, 0, stream>>>(adj0, At, 1024, 1024, 0, 0);
  k_prep<<<dim3(4, 4, 1), 256, 0, stream>>>(adj1, A1t, 256, 256, 0, 0);

  for (int c0 = 0; c0 < BB; c0 += nb_max) {
    const int nb = (BB - c0 < nb_max) ? (BB - c0) : nb_max;
    const float* xc = x   + (size_t)c0 * SLICE;
    float*       oc = out + (size_t)c0 * SLICE;

    k_prep<<<dim3(NCOL / 64, 16, nb), 256, 0, stream>>>(
        xc, Xt, NCOL, 1024, SLICE, (size_t)NCOL * 1024);

    dim3 g1(nb * 32, 8);
    k_mode0_mfma<<<g1, 256, 0, stream>>>(At, Xt, y0);

    k_proj<<<dim3(nb * NN1), 256, 0, stream>>>(xc, y0, st, rb, W, bW, Ws0, bs0,
                                               Ws1, bs1, Ws01, bs01);

    dim3 g2(2, nb * 128);
    k_mode1c<<<g2, 256, 0, stream>>>(A1t, st, rb, oc);
  }
}

// Round 9
// 277.399 us; speedup vs baseline: 1.0363x; 1.0095x over previous
//
#include <hip/hip_runtime.h>

#define BB  8
#define NN1 1024
#define NN2 256
#define DD  16
#define EE  16
#define NCOL (NN2 * DD)   // 4096

using bf16x8  = __attribute__((ext_vector_type(8))) short;
using f32x4   = __attribute__((ext_vector_type(4))) float;
using ushort8 = __attribute__((ext_vector_type(8))) unsigned short;

__device__ __forceinline__ ushort f2bf(float x) {
  unsigned u = __float_as_uint(x);
  unsigned r = (u + 0x7FFFu + ((u >> 16) & 1u)) >> 16;
  return (ushort)r;
}
__device__ __forceinline__ float bf2f(ushort u) {
  return __uint_as_float((unsigned)u << 16);
}
__device__ __forceinline__ unsigned pkbf(float a, float b) {
  return (unsigned)f2bf(a) | ((unsigned)f2bf(b) << 16);
}

#define GLDS16(g, l)                                                       \
  __builtin_amdgcn_global_load_lds(                                        \
      (const __attribute__((address_space(1))) void*)(g),                  \
      (__attribute__((address_space(3))) void*)(l), 16, 0, 0)

// ---------------------------------------------------------------------------
// k_prep: transpose + fp32->bf16 + 16B-chunk swizzle.
// src fp32 [kd(k)][nr], dst bf16 [nr][kd], chunk g <- g ^ ((row>>1)&3) per 64B.
// ---------------------------------------------------------------------------
__global__ __launch_bounds__(256)
void k_prep(const float* __restrict__ src, ushort* __restrict__ dst,
            int nr, int kd, size_t srcBatch, size_t dstBatch) {
  __shared__ float tile[64][65];
  const int t = threadIdx.x;
  const int r0 = blockIdx.x * 64;
  const int k0 = blockIdx.y * 64;
  const float* s = src + (size_t)blockIdx.z * srcBatch;
  ushort* d = dst + (size_t)blockIdx.z * dstBatch;

#pragma unroll
  for (int it = 0; it < 4; ++it) {
    const int kr = it * 16 + (t >> 4);
    const int rc = (t & 15) * 4;
    float4 v = *reinterpret_cast<const float4*>(&s[(size_t)(k0 + kr) * nr + r0 + rc]);
    tile[kr][rc] = v.x; tile[kr][rc + 1] = v.y;
    tile[kr][rc + 2] = v.z; tile[kr][rc + 3] = v.w;
  }
  __syncthreads();

#pragma unroll
  for (int pass = 0; pass < 2; ++pass) {
    const int task = t + pass * 256;
    const int pr = task >> 3;
    const int gl = task & 7;
    const int r = r0 + pr;
    const int f = (r >> 1) & 3;
    const int klb = (gl >> 2) * 32 + ((gl & 3) ^ f) * 8;
    unsigned w[4];
#pragma unroll
    for (int e2 = 0; e2 < 4; ++e2)
      w[e2] = pkbf(tile[klb + e2 * 2][pr], tile[klb + e2 * 2 + 1][pr]);
    *reinterpret_cast<uint4*>(&d[(size_t)r * kd + k0 + gl * 8]) =
        *reinterpret_cast<const uint4*>(w);
  }
}

// ---------------------------------------------------------------------------
// k_mode0_mfma: y[b][p][c] = sum_k adj0[k][p] * X[b][k][c] -> bf16
// 128x128 block tile, BK=32, TWO waves x (128m x 64n) wave-tiles:
// 42.7 FLOP per LDS byte (vs 16 at 64x64) -- LDS-pressure fix.
// 2-phase pipeline, counted vmcnt(8), raw s_barrier.
// ---------------------------------------------------------------------------
__global__ __launch_bounds__(128, 2)
void k_mode0_mfma(const ushort* __restrict__ At, const ushort* __restrict__ Xt,
                  ushort* __restrict__ Y) {
  __shared__ ushort As[2][4096];
  __shared__ ushort Bs[2][4096];

  const int t = threadIdx.x;
  const int lane = t & 63;
  const int wid = t >> 6;          // 0..1, splits the 128-wide N dimension
  const int b  = blockIdx.x >> 5;
  const int c0 = (blockIdx.x & 31) << 7;
  const int p0 = blockIdx.y << 7;

  const ushort* Bb = Xt + (size_t)b * (NCOL * 1024);

  f32x4 acc[8][4];
#pragma unroll
  for (int i = 0; i < 8; ++i)
#pragma unroll
    for (int j = 0; j < 4; ++j) acc[i][j] = (f32x4)0.f;

  // staging: per wave-issue 16 rows (64 lanes x 16B); 4 issues per operand
  const int srow = wid * 16 + (lane >> 2);   // row within a 32-row issue pair
  const int schk = (lane & 3) * 8;
  const size_t aoff0 = (size_t)(p0 + srow) * 1024 + schk;
  const size_t boff0 = (size_t)(c0 + srow) * 1024 + schk;
  const int ldst = wid * 512;                // ushorts: 16 rows x 32

  const int lm = lane & 15, g = lane >> 4;
  int aro[8], bro[4];
#pragma unroll
  for (int f = 0; f < 8; ++f) {
    const int ra = f * 16 + lm;
    aro[f] = ra * 32 + ((g ^ ((ra >> 1) & 3)) << 3);
  }
#pragma unroll
  for (int f = 0; f < 4; ++f) {
    const int rw = wid * 64 + f * 16 + lm;
    bro[f] = rw * 32 + ((g ^ ((rw >> 1) & 3)) << 3);
  }

#define STAGE0(buf, kk)                                                    \
  do {                                                                     \
    _Pragma("unroll")                                                      \
    for (int is = 0; is < 4; ++is) {                                       \
      GLDS16(At + aoff0 + (size_t)is * 32 * 1024 + (kk),                   \
             &As[buf][is * 1024 + ldst]);                                  \
      GLDS16(Bb + boff0 + (size_t)is * 32 * 1024 + (kk),                   \
             &Bs[buf][is * 1024 + ldst]);                                  \
    }                                                                      \
  } while (0)

  STAGE0(0, 0);
  int cur = 0;

  for (int k0 = 0; k0 < 1024; k0 += 32) {
    if (k0 + 32 < 1024) {
      STAGE0(cur ^ 1, k0 + 32);
      asm volatile("s_waitcnt vmcnt(8)" ::: "memory");
    } else {
      asm volatile("s_waitcnt vmcnt(0)" ::: "memory");
    }
    __builtin_amdgcn_s_barrier();
    __builtin_amdgcn_sched_barrier(0);

    bf16x8 af[8], bfr[4];
#pragma unroll
    for (int f = 0; f < 8; ++f)
      af[f] = *reinterpret_cast<const bf16x8*>(&As[cur][aro[f]]);
#pragma unroll
    for (int f = 0; f < 4; ++f)
      bfr[f] = *reinterpret_cast<const bf16x8*>(&Bs[cur][bro[f]]);

#pragma unroll
    for (int i = 0; i < 8; ++i)
#pragma unroll
      for (int j = 0; j < 4; ++j)
        acc[i][j] = __builtin_amdgcn_mfma_f32_16x16x32_bf16(af[i], bfr[j], acc[i][j], 0, 0, 0);

    __builtin_amdgcn_sched_barrier(0);
    __builtin_amdgcn_s_barrier();
    cur ^= 1;
  }
#undef STAGE0

  ushort* Yb = Y + (size_t)b * (NN1 * NCOL);
  const int orow = g * 4;
  const int ocol = lm;
#pragma unroll
  for (int i = 0; i < 8; ++i)
#pragma unroll
    for (int j = 0; j < 4; ++j) {
      const int p = p0 + i * 16 + orow;
      const int c = c0 + wid * 64 + j * 16 + ocol;
      ushort* dst = Yb + (size_t)p * NCOL + c;
#pragma unroll
      for (int e = 0; e < 4; ++e) dst[(size_t)e * NCOL] = f2bf(acc[i][j][e]);
    }
}

// ---------------------------------------------------------------------------
// k_proj: per (b,p) slice, thread j:
//   r[j,e] = x@W + y0@W_s0 + sum(bias)  -> rb (bf16, [slice][j][e])
//   s[j,e] = x@W_s1 + y0@W_s01          -> st (bf16, swizzled, [slice*16+e][j])
// ---------------------------------------------------------------------------
__global__ __launch_bounds__(256)
void k_proj(const float* __restrict__ x, const ushort* __restrict__ y0,
            ushort* __restrict__ st, ushort* __restrict__ rb,
            const float* __restrict__ W,   const float* __restrict__ bW,
            const float* __restrict__ W0,  const float* __restrict__ b0,
            const float* __restrict__ W1,  const float* __restrict__ b1,
            const float* __restrict__ W01, const float* __restrict__ b01) {
  __shared__ float sW[4][DD][EE];
  __shared__ float sbias[EE];

  const int t = threadIdx.x;
  {
    const int m = t >> 6;
    const int r = t & 63;
    const float* Wp = (m == 0) ? W : (m == 1) ? W0 : (m == 2) ? W1 : W01;
    reinterpret_cast<float4*>(&sW[m][0][0])[r] =
        reinterpret_cast<const float4*>(Wp)[r];
  }
  if (t < EE) sbias[t] = bW[t] + b0[t] + b1[t] + b01[t];
  __syncthreads();

  const size_t base = (size_t)blockIdx.x * NCOL + (size_t)t * DD;

  float xr[DD], yr[DD];
#pragma unroll
  for (int v = 0; v < 4; ++v)
    *reinterpret_cast<float4*>(&xr[v * 4]) =
        *reinterpret_cast<const float4*>(&x[base + v * 4]);
  {
    ushort8 ya = *reinterpret_cast<const ushort8*>(&y0[base]);
    ushort8 yb = *reinterpret_cast<const ushort8*>(&y0[base + 8]);
#pragma unroll
    for (int k = 0; k < 8; ++k) { yr[k] = bf2f(ya[k]); yr[8 + k] = bf2f(yb[k]); }
  }

  float r[EE], s[EE];
#pragma unroll
  for (int e = 0; e < EE; ++e) { r[e] = sbias[e]; s[e] = 0.f; }

#pragma unroll
  for (int d = 0; d < DD; ++d) {
    const float xd = xr[d], yd = yr[d];
#pragma unroll
    for (int e = 0; e < EE; ++e) {
      r[e] = fmaf(xd, sW[0][d][e], r[e]);
      r[e] = fmaf(yd, sW[1][d][e], r[e]);
      s[e] = fmaf(xd, sW[2][d][e], s[e]);
      s[e] = fmaf(yd, sW[3][d][e], s[e]);
    }
  }

  {
    ushort rw[16];
#pragma unroll
    for (int e = 0; e < EE; ++e) rw[e] = f2bf(r[e]);
    *reinterpret_cast<uint4*>(&rb[base])     = *reinterpret_cast<const uint4*>(&rw[0]);
    *reinterpret_cast<uint4*>(&rb[base + 8]) = *reinterpret_cast<const uint4*>(&rw[8]);
  }

  const size_t stbase = (size_t)blockIdx.x * (EE * NN2);
#pragma unroll
  for (int e = 0; e < EE; ++e) {
    const int f = (e >> 1) & 3;
    const int off = (t >> 5) * 32 + ((((t >> 3) & 3) ^ f) << 3) + (t & 7);
    st[stbase + (size_t)e * NN2 + off] = f2bf(s[e]);
  }
}

// ---------------------------------------------------------------------------
// k_mode1c: C[q][m] = sum_j adj1t[q][j] * st[m][j]   (m = slice*16+e)
// out[slice][q][e] = relu(rb + C).  A,B GLDS16-staged, 2-phase pipeline,
// T14 rb pre-stage into Rs.
// ---------------------------------------------------------------------------
__global__ __launch_bounds__(256)
void k_mode1c(const ushort* __restrict__ A1t, const ushort* __restrict__ st,
              const ushort* __restrict__ rb, float* __restrict__ out) {
  __shared__ ushort As[2][4096];
  __shared__ ushort Bs[2][4096];
  __shared__ ushort Rs[16384];     // 8 sl x 128 q x 16 e

  const int t = threadIdx.x;
  const int lane = t & 63;
  const int wid = t >> 6;
  const int wm = wid >> 1, wn = wid & 1;
  const int q0  = blockIdx.x << 7;
  const int m0  = blockIdx.y << 7;
  const int sl0 = blockIdx.y << 3;

#pragma unroll
  for (int k = 0; k < 8; ++k) {
    const ushort* gsrc = rb + (size_t)(sl0 + k) * NCOL + q0 * 16 + (wid * 64 + lane) * 8;
    GLDS16(gsrc, &Rs[k * 2048 + wid * 512]);
  }

  f32x4 acc[4][4];
#pragma unroll
  for (int i = 0; i < 4; ++i)
#pragma unroll
    for (int j = 0; j < 4; ++j) acc[i][j] = (f32x4)0.f;

  const int srow = wid * 32 + (lane >> 2);
  const int schk = (lane & 3) * 8;
  const size_t aoff0 = (size_t)(q0 + srow) * 256 + schk;
  const size_t boff0 = (size_t)(m0 + srow) * 256 + schk;
  const int lw0 = (wid * 32) * 32;
  const int lw1 = (wid * 32 + 16) * 32;

  const int lm = lane & 15, g = lane >> 4;
  int aro[4], bro[4];
#pragma unroll
  for (int f = 0; f < 4; ++f) {
    const int ra = wm * 64 + f * 16 + lm;
    aro[f] = ra * 32 + ((g ^ ((ra >> 1) & 3)) << 3);
    const int rw = wn * 64 + f * 16 + lm;
    bro[f] = rw * 32 + ((g ^ ((rw >> 1) & 3)) << 3);
  }

#define STAGE1(buf, kk)                                                    \
  do {                                                                     \
    GLDS16(A1t + aoff0 + (kk), &As[buf][lw0]);                             \
    GLDS16(A1t + aoff0 + 16 * 256 + (kk), &As[buf][lw1]);                  \
    GLDS16(st + boff0 + (kk), &Bs[buf][lw0]);                              \
    GLDS16(st + boff0 + 16 * 256 + (kk), &Bs[buf][lw1]);                   \
  } while (0)

  STAGE1(0, 0);
  int cur = 0;

  for (int k0 = 0; k0 < 256; k0 += 32) {
    if (k0 + 32 < 256) {
      STAGE1(cur ^ 1, k0 + 32);
      asm volatile("s_waitcnt vmcnt(4)" ::: "memory");
    } else {
      asm volatile("s_waitcnt vmcnt(0)" ::: "memory");
    }
    __builtin_amdgcn_s_barrier();
    __builtin_amdgcn_sched_barrier(0);

    bf16x8 af[4], bfr[4];
#pragma unroll
    for (int f = 0; f < 4; ++f)
      af[f] = *reinterpret_cast<const bf16x8*>(&As[cur][aro[f]]);
#pragma unroll
    for (int f = 0; f < 4; ++f)
      bfr[f] = *reinterpret_cast<const bf16x8*>(&Bs[cur][bro[f]]);

#pragma unroll
    for (int i = 0; i < 4; ++i)
#pragma unroll
      for (int j = 0; j < 4; ++j)
        acc[i][j] = __builtin_amdgcn_mfma_f32_16x16x32_bf16(af[i], bfr[j], acc[i][j], 0, 0, 0);

    __builtin_amdgcn_sched_barrier(0);
    __builtin_amdgcn_s_barrier();
    cur ^= 1;
  }
#undef STAGE1

  const int orow = g * 4;
#pragma unroll
  for (int i = 0; i < 4; ++i)
#pragma unroll
    for (int j = 0; j < 4; ++j) {
      const int ml  = wn * 64 + j * 16 + lm;
      const int bpl = ml >> 4, e = ml & 15;
      const int ql  = wm * 64 + i * 16 + orow;
      const ushort* rsl = &Rs[bpl * 2048 + ql * 16 + e];
      float* dst = out + (size_t)(sl0 + bpl) * NCOL + (size_t)(q0 + ql) * EE + e;
#pragma unroll
      for (int r = 0; r < 4; ++r)
        dst[r * EE] = fmaxf(bf2f(rsl[r * 16]) + acc[i][j][r], 0.f);
    }
}

// ---------------------------------------------------------------------------
extern "C" void kernel_launch(void* const* d_in, const int* in_sizes, int n_in,
                              void* d_out, int out_size, void* d_ws, size_t ws_size,
                              hipStream_t stream) {
  const float* x    = (const float*)d_in[0];
  const float* adj0 = (const float*)d_in[1];
  const float* adj1 = (const float*)d_in[2];
  const float* W    = (const float*)d_in[3];
  const float* bW   = (const float*)d_in[4];
  const float* Ws0  = (const float*)d_in[5];
  const float* bs0  = (const float*)d_in[6];
  const float* Ws1  = (const float*)d_in[7];
  const float* bs1  = (const float*)d_in[8];
  const float* Ws01 = (const float*)d_in[9];
  const float* bs01 = (const float*)d_in[10];
  float* out = (float*)d_out;

  const size_t SLICE = (size_t)NN1 * NCOL;
  const size_t AT_B  = (size_t)1024 * 1024 * 2;
  const size_t A1T_B = (size_t)256 * 256 * 2;
  const size_t XT_B  = (size_t)NCOL * 1024 * 2;
  const size_t Y0_B  = SLICE * 2;
  const size_t ST_B  = SLICE * 2;
  const size_t RB_B  = SLICE * 2;
  const size_t HEAD  = AT_B + A1T_B;
  const size_t PER_B = XT_B + Y0_B + ST_B + RB_B;

  int nb_max = (int)((ws_size > HEAD ? ws_size - HEAD : 0) / PER_B);
  if (nb_max > BB) nb_max = BB;
  if (nb_max < 1)  nb_max = 1;

  ushort* At  = (ushort*)d_ws;
  ushort* A1t = (ushort*)((char*)d_ws + AT_B);
  ushort* Xt  = (ushort*)((char*)d_ws + HEAD);
  ushort* y0  = (ushort*)((char*)d_ws + HEAD + (size_t)nb_max * XT_B);
  ushort* st  = (ushort*)((char*)d_ws + HEAD + (size_t)nb_max * (XT_B + Y0_B));
  ushort* rb  = (ushort*)((char*)d_ws + HEAD + (size_t)nb_max * (XT_B + Y0_B + ST_B));

  k_prep<<<dim3(16, 16, 1), 256, 0, stream>>>(adj0, At, 1024, 1024, 0, 0);
  k_prep<<<dim3(4, 4, 1), 256, 0, stream>>>(adj1, A1t, 256, 256, 0, 0);

  for (int c0 = 0; c0 < BB; c0 += nb_max) {
    const int nb = (BB - c0 < nb_max) ? (BB - c0) : nb_max;
    const float* xc = x   + (size_t)c0 * SLICE;
    float*       oc = out + (size_t)c0 * SLICE;

    k_prep<<<dim3(NCOL / 64, 16, nb), 256, 0, stream>>>(
        xc, Xt, NCOL, 1024, SLICE, (size_t)NCOL * 1024);

    dim3 g1(nb * 32, 8);
    k_mode0_mfma<<<g1, 128, 0, stream>>>(At, Xt, y0);

    k_proj<<<dim3(nb * NN1), 256, 0, stream>>>(xc, y0, st, rb, W, bW, Ws0, bs0,
                                               Ws1, bs1, Ws01, bs01);

    dim3 g2(2, nb * 128);
    k_mode1c<<<g2, 256, 0, stream>>>(A1t, st, rb, oc);
  }
}